// Round 2
// baseline (138.591 us; speedup 1.0000x reference)
//
#include <hip/hip_runtime.h>

// Block Hadamard (block=128) = natural-order FWHT * 1/sqrt(128).
// Layout v2: each lane owns 16 CONTIGUOUS elements (4 x float4 = 64B).
//   element index bits [3:0] -> in-register  (stages h=1,2,4,8 : pure VALU)
//   element index bits [6:4] -> lane bits    (stages h=16,32,64 : shfl_xor 1,2,4)
// 3 shuffle stages x 16 independent values each -> deep ILP, latency-tolerant.

__global__ __launch_bounds__(256) void BlockHadamardTransform_88957362634992_kernel(
    const float4* __restrict__ x, float4* __restrict__ y, int n16) {
    const float scale = 0.08838834764831845f;  // 1/sqrt(128)
    const int j = threadIdx.x & 7;             // lane bits within a 128-block
    const int stride = gridDim.x * blockDim.x;
    for (int c = blockIdx.x * blockDim.x + threadIdx.x; c < n16; c += stride) {
        const int base = c * 4;
        float r[16];
        #pragma unroll
        for (int k = 0; k < 4; ++k) {
            float4 v = x[base + k];
            r[4 * k + 0] = v.x;
            r[4 * k + 1] = v.y;
            r[4 * k + 2] = v.z;
            r[4 * k + 3] = v.w;
        }
        // in-register butterfly stages h = 1,2,4,8
        #pragma unroll
        for (int h = 1; h <= 8; h <<= 1) {
            #pragma unroll
            for (int i = 0; i < 16; ++i) {
                if ((i & h) == 0) {
                    float lo = r[i], hi = r[i ^ h];
                    r[i] = lo + hi;
                    r[i ^ h] = lo - hi;
                }
            }
        }
        // cross-lane stages h = 16,32,64  -> masks 1,2,4
        #pragma unroll
        for (int m = 1; m <= 4; m <<= 1) {
            const bool up = (j & m) != 0;
            #pragma unroll
            for (int i = 0; i < 16; ++i) {
                float p = __shfl_xor(r[i], m);
                r[i] = up ? (p - r[i]) : (r[i] + p);
            }
        }
        #pragma unroll
        for (int k = 0; k < 4; ++k) {
            float4 o;
            o.x = r[4 * k + 0] * scale;
            o.y = r[4 * k + 1] * scale;
            o.z = r[4 * k + 2] * scale;
            o.w = r[4 * k + 3] * scale;
            y[base + k] = o;
        }
    }
}

extern "C" void kernel_launch(void* const* d_in, const int* in_sizes, int n_in,
                              void* d_out, int out_size, void* d_ws, size_t ws_size,
                              hipStream_t stream) {
    const float4* x = (const float4*)d_in[0];
    float4* y = (float4*)d_out;
    const int n16 = out_size / 16;  // 67,108,864 elems / 16 per lane-iter = 4,194,304
    const int threads = 256;
    const int blocks = 2048;  // 8 blocks/CU = 32 waves/CU; 8 grid-stride iters
    BlockHadamardTransform_88957362634992_kernel<<<blocks, threads, 0, stream>>>(x, y, n16);
}

// Round 3
// 101.995 us; speedup vs baseline: 1.3588x; 1.3588x over previous
//
#include <hip/hip_runtime.h>

// Block Hadamard (block=128) = natural-order FWHT * 1/sqrt(128).
// v3: coalesced + 16 elems/lane ILP.
//   Each wave owns a contiguous 4 KB chunk = 8 blocks = 256 float4s.
//   Load k (k=0..3): lane l reads float4 index c*256 + 64k + l  -> every
//   instruction is 64 lanes x contiguous 16 B = perfectly coalesced 1 KB.
//   Lane's 4 registers = same position p = l&31 in 4 different blocks
//   (block = 2k + (l>>5)), so:
//     element bits [1:0] -> in-float4   (stages h=1,2  : pure VALU)
//     position bits l[4:0] -> lane bits (stages h=4..64: shfl_xor 1,2,4,8,16)
//   5 shuffle stages x 16 independent values each -> 4x the ILP of v1 at
//   identical memory pattern.

__global__ __launch_bounds__(256) void BlockHadamardTransform_88957362634992_kernel(
    const float4* __restrict__ x, float4* __restrict__ y, int nchunks, int nwaves) {
    const float scale = 0.08838834764831845f;  // 1/sqrt(128)
    const int t = blockIdx.x * blockDim.x + threadIdx.x;
    const int w = t >> 6;
    const int lane = t & 63;
    for (int c = w; c < nchunks; c += nwaves) {
        const size_t base = (size_t)c * 256 + lane;
        float r[16];
        #pragma unroll
        for (int k = 0; k < 4; ++k) {
            float4 v = x[base + 64 * k];
            r[4 * k + 0] = v.x;
            r[4 * k + 1] = v.y;
            r[4 * k + 2] = v.z;
            r[4 * k + 3] = v.w;
        }
        // stages h=1,2 : within each float4 (independent across the 4 blocks)
        #pragma unroll
        for (int k = 0; k < 4; ++k) {
            float a0 = r[4 * k + 0] + r[4 * k + 1];
            float a1 = r[4 * k + 0] - r[4 * k + 1];
            float a2 = r[4 * k + 2] + r[4 * k + 3];
            float a3 = r[4 * k + 2] - r[4 * k + 3];
            r[4 * k + 0] = a0 + a2;
            r[4 * k + 1] = a1 + a3;
            r[4 * k + 2] = a0 - a2;
            r[4 * k + 3] = a1 - a3;
        }
        // stages h=4..64 : xor on lane bits [4:0]; masks <=16 stay inside each
        // 32-lane half (the two halves hold different blocks). 16-way ILP/stage.
        #pragma unroll
        for (int m = 1; m <= 16; m <<= 1) {
            const bool up = (lane & m) != 0;
            #pragma unroll
            for (int i = 0; i < 16; ++i) {
                float p = __shfl_xor(r[i], m);
                r[i] = up ? (p - r[i]) : (r[i] + p);
            }
        }
        #pragma unroll
        for (int k = 0; k < 4; ++k) {
            float4 o;
            o.x = r[4 * k + 0] * scale;
            o.y = r[4 * k + 1] * scale;
            o.z = r[4 * k + 2] * scale;
            o.w = r[4 * k + 3] * scale;
            y[base + 64 * k] = o;
        }
    }
}

extern "C" void kernel_launch(void* const* d_in, const int* in_sizes, int n_in,
                              void* d_out, int out_size, void* d_ws, size_t ws_size,
                              hipStream_t stream) {
    const float4* x = (const float4*)d_in[0];
    float4* y = (float4*)d_out;
    const int threads = 256;
    const int blocks = 2048;                     // 8192 waves
    const int nwaves = blocks * threads / 64;    // 8192
    const int nchunks = out_size / 1024;         // 1024 elems (4 KB) per wave-chunk = 65536
    BlockHadamardTransform_88957362634992_kernel<<<blocks, threads, 0, stream>>>(x, y, nchunks, nwaves);
}

// Round 4
// 101.186 us; speedup vs baseline: 1.3697x; 1.0080x over previous
//
#include <hip/hip_runtime.h>

// Block Hadamard (block=128) = natural-order FWHT * 1/sqrt(128).
// v5 = v3 memory layout (perfectly coalesced 1KB segments, 16 elems/lane)
//      + DPP quad_perm for the two finest cross-lane stages (VALU pipe,
//        not DS pipe) + sign-FMA butterflies (1 VALU instead of 3).
//
// Stage map (element stride h -> lane xor mask):
//   h=1,2   : inside the float4 (pure VALU add/sub)
//   h=4     : lane^1  -> DPP quad_perm [1,0,3,2] (0xB1)   VALU pipe
//   h=8     : lane^2  -> DPP quad_perm [2,3,0,1] (0x4E)   VALU pipe
//   h=16,32,64 : lane^{4,8,16} -> __shfl_xor               DS pipe (48 ops/chunk)

__device__ __forceinline__ float dpp_xor1(float v) {
    int i = __float_as_int(v);
    int r = __builtin_amdgcn_update_dpp(i, i, 0xB1, 0xF, 0xF, true);
    return __int_as_float(r);
}
__device__ __forceinline__ float dpp_xor2(float v) {
    int i = __float_as_int(v);
    int r = __builtin_amdgcn_update_dpp(i, i, 0x4E, 0xF, 0xF, true);
    return __int_as_float(r);
}

__global__ __launch_bounds__(256) void BlockHadamardTransform_88957362634992_kernel(
    const float4* __restrict__ x, float4* __restrict__ y, int nchunks, int nwaves) {
    const float scale = 0.08838834764831845f;  // 1/sqrt(128)
    const int t = blockIdx.x * blockDim.x + threadIdx.x;
    const int w = t >> 6;
    const int lane = t & 63;
    // sign registers for the sign-FMA butterfly: +1 if partner adds, -1 if this
    // lane is the "upper" element of the pair
    const float s1 = (lane & 1) ? -1.f : 1.f;
    const float s2 = (lane & 2) ? -1.f : 1.f;
    const float s4 = (lane & 4) ? -1.f : 1.f;
    const float s8 = (lane & 8) ? -1.f : 1.f;
    const float s16 = (lane & 16) ? -1.f : 1.f;
    for (int c = w; c < nchunks; c += nwaves) {
        const size_t base = (size_t)c * 256 + lane;
        float r[16];
        #pragma unroll
        for (int k = 0; k < 4; ++k) {
            float4 v = x[base + 64 * k];
            r[4 * k + 0] = v.x;
            r[4 * k + 1] = v.y;
            r[4 * k + 2] = v.z;
            r[4 * k + 3] = v.w;
        }
        // stages h=1,2 : within each float4
        #pragma unroll
        for (int k = 0; k < 4; ++k) {
            float a0 = r[4 * k + 0] + r[4 * k + 1];
            float a1 = r[4 * k + 0] - r[4 * k + 1];
            float a2 = r[4 * k + 2] + r[4 * k + 3];
            float a3 = r[4 * k + 2] - r[4 * k + 3];
            r[4 * k + 0] = a0 + a2;
            r[4 * k + 1] = a1 + a3;
            r[4 * k + 2] = a0 - a2;
            r[4 * k + 3] = a1 - a3;
        }
        // h=4 : lane^1 via DPP (VALU)
        #pragma unroll
        for (int i = 0; i < 16; ++i) {
            float p = dpp_xor1(r[i]);
            r[i] = fmaf(s1, r[i], p);
        }
        // h=8 : lane^2 via DPP (VALU)
        #pragma unroll
        for (int i = 0; i < 16; ++i) {
            float p = dpp_xor2(r[i]);
            r[i] = fmaf(s2, r[i], p);
        }
        // h=16,32,64 : lane^{4,8,16} via shfl (DS pipe)
        #pragma unroll
        for (int i = 0; i < 16; ++i) {
            float p = __shfl_xor(r[i], 4);
            r[i] = fmaf(s4, r[i], p);
        }
        #pragma unroll
        for (int i = 0; i < 16; ++i) {
            float p = __shfl_xor(r[i], 8);
            r[i] = fmaf(s8, r[i], p);
        }
        #pragma unroll
        for (int i = 0; i < 16; ++i) {
            float p = __shfl_xor(r[i], 16);
            r[i] = fmaf(s16, r[i], p);
        }
        #pragma unroll
        for (int k = 0; k < 4; ++k) {
            float4 o;
            o.x = r[4 * k + 0] * scale;
            o.y = r[4 * k + 1] * scale;
            o.z = r[4 * k + 2] * scale;
            o.w = r[4 * k + 3] * scale;
            y[base + 64 * k] = o;
        }
    }
}

extern "C" void kernel_launch(void* const* d_in, const int* in_sizes, int n_in,
                              void* d_out, int out_size, void* d_ws, size_t ws_size,
                              hipStream_t stream) {
    const float4* x = (const float4*)d_in[0];
    float4* y = (float4*)d_out;
    const int threads = 256;
    const int blocks = 2048;                     // 8 WG/CU, 32 waves/CU
    const int nwaves = blocks * threads / 64;    // 8192
    const int nchunks = out_size / 1024;         // 65536 chunks of 4 KB
    BlockHadamardTransform_88957362634992_kernel<<<blocks, threads, 0, stream>>>(x, y, nchunks, nwaves);
}

// Round 6
// 83.227 us; speedup vs baseline: 1.6652x; 1.2158x over previous
//
#include <hip/hip_runtime.h>

// Block Hadamard (block=128) = natural-order FWHT * 1/sqrt(128).
// v7 = v5 (coalesced 1KB segments, 16 elems/lane, DPP fine stages,
//      sign-FMA butterflies) + NONTEMPORAL stores via native vector type
//      (__builtin_nontemporal_store rejects HIP_vector_type; use
//       ext_vector_type(4) float, same global_store_dwordx4 + nt flag).
// Rationale: output is never re-read; write-allocate evicts the input
// (268 MB vs 256 MiB L3) between graph replays. NT stores keep L3 for
// the read stream.

typedef float f32x4 __attribute__((ext_vector_type(4)));

__device__ __forceinline__ float dpp_xor1(float v) {
    int i = __float_as_int(v);
    int r = __builtin_amdgcn_update_dpp(i, i, 0xB1, 0xF, 0xF, true);
    return __int_as_float(r);
}
__device__ __forceinline__ float dpp_xor2(float v) {
    int i = __float_as_int(v);
    int r = __builtin_amdgcn_update_dpp(i, i, 0x4E, 0xF, 0xF, true);
    return __int_as_float(r);
}

__global__ __launch_bounds__(256) void BlockHadamardTransform_88957362634992_kernel(
    const f32x4* __restrict__ x, f32x4* __restrict__ y, int nchunks, int nwaves) {
    const float scale = 0.08838834764831845f;  // 1/sqrt(128)
    const int t = blockIdx.x * blockDim.x + threadIdx.x;
    const int w = t >> 6;
    const int lane = t & 63;
    const float s1 = (lane & 1) ? -1.f : 1.f;
    const float s2 = (lane & 2) ? -1.f : 1.f;
    const float s4 = (lane & 4) ? -1.f : 1.f;
    const float s8 = (lane & 8) ? -1.f : 1.f;
    const float s16 = (lane & 16) ? -1.f : 1.f;
    for (int c = w; c < nchunks; c += nwaves) {
        const size_t base = (size_t)c * 256 + lane;
        float r[16];
        #pragma unroll
        for (int k = 0; k < 4; ++k) {
            f32x4 v = x[base + 64 * k];
            r[4 * k + 0] = v.x;
            r[4 * k + 1] = v.y;
            r[4 * k + 2] = v.z;
            r[4 * k + 3] = v.w;
        }
        // stages h=1,2 : within each float4
        #pragma unroll
        for (int k = 0; k < 4; ++k) {
            float a0 = r[4 * k + 0] + r[4 * k + 1];
            float a1 = r[4 * k + 0] - r[4 * k + 1];
            float a2 = r[4 * k + 2] + r[4 * k + 3];
            float a3 = r[4 * k + 2] - r[4 * k + 3];
            r[4 * k + 0] = a0 + a2;
            r[4 * k + 1] = a1 + a3;
            r[4 * k + 2] = a0 - a2;
            r[4 * k + 3] = a1 - a3;
        }
        // h=4 : lane^1 via DPP (VALU pipe)
        #pragma unroll
        for (int i = 0; i < 16; ++i) {
            float p = dpp_xor1(r[i]);
            r[i] = fmaf(s1, r[i], p);
        }
        // h=8 : lane^2 via DPP (VALU pipe)
        #pragma unroll
        for (int i = 0; i < 16; ++i) {
            float p = dpp_xor2(r[i]);
            r[i] = fmaf(s2, r[i], p);
        }
        // h=16,32,64 : lane^{4,8,16} via shfl (DS pipe)
        #pragma unroll
        for (int i = 0; i < 16; ++i) {
            float p = __shfl_xor(r[i], 4);
            r[i] = fmaf(s4, r[i], p);
        }
        #pragma unroll
        for (int i = 0; i < 16; ++i) {
            float p = __shfl_xor(r[i], 8);
            r[i] = fmaf(s8, r[i], p);
        }
        #pragma unroll
        for (int i = 0; i < 16; ++i) {
            float p = __shfl_xor(r[i], 16);
            r[i] = fmaf(s16, r[i], p);
        }
        #pragma unroll
        for (int k = 0; k < 4; ++k) {
            f32x4 o;
            o.x = r[4 * k + 0] * scale;
            o.y = r[4 * k + 1] * scale;
            o.z = r[4 * k + 2] * scale;
            o.w = r[4 * k + 3] * scale;
            __builtin_nontemporal_store(o, &y[base + 64 * k]);
        }
    }
}

extern "C" void kernel_launch(void* const* d_in, const int* in_sizes, int n_in,
                              void* d_out, int out_size, void* d_ws, size_t ws_size,
                              hipStream_t stream) {
    const f32x4* x = (const f32x4*)d_in[0];
    f32x4* y = (f32x4*)d_out;
    const int threads = 256;
    const int blocks = 2048;                     // 8 WG/CU, 32 waves/CU
    const int nwaves = blocks * threads / 64;    // 8192
    const int nchunks = out_size / 1024;         // 65536 chunks of 4 KB
    BlockHadamardTransform_88957362634992_kernel<<<blocks, threads, 0, stream>>>(x, y, nchunks, nwaves);
}